// Round 7
// baseline (36.383 us; speedup 1.0000x reference)
//
#include <hip/hip_runtime.h>

// ---------------- problem constants ----------------
#define B_    8192
#define K_    784      // IN_DIM
#define KP    832      // K padded to 26*32
#define NKB   26       // K blocks of 32
#define RP    1024     // unique w1 rows = HIDDEN/CF
#define HID   4096
#define OD    10
#define TS2   10240    // OUT_DIM*HIDDEN/CF

#define NB_X  3328     // 8192*104/256
#define NB_S  416      // 1024*104/256
#define NB_F  64       // 16*1024/256  (Vfrag)
#define NB_Z  80       // 80*256*4 = 81920 floats of out zeroing

typedef __attribute__((ext_vector_type(8))) short  bf16x8;
typedef __attribute__((ext_vector_type(4))) float  f32x4;

__device__ __forceinline__ unsigned short f2bf(float f) {
    unsigned u = __builtin_bit_cast(unsigned, f);
    u += 0x7fffu + ((u >> 16) & 1u);          // RNE
    return (unsigned short)(u >> 16);
}

// ================= merged prep kernel =====================================
// blocks [0, NB_X)     : x -> bf16, padded, 4-slot xi-swizzled rows
// blocks [NB_X, +NB_S) : tile1 -> +/-1 bf16, same layout
// blocks [.., +NB_F)   : Vfrag (bf16, MFMA B-fragment order, o pad to 16)
// blocks [.., +NB_Z)   : zero out[]
// Layout: Arr[row][kb][s][e] = src[row][kb*32 + (s ^ xi(row))*8 + e],
//         xi(row) = (row ^ (row>>2)) & 3, zero beyond col 784.
__global__ __launch_bounds__(256) void prep(
    const float* __restrict__ x, const int* __restrict__ t1,
    const int* __restrict__ t2, const float* __restrict__ a1,
    const float* __restrict__ a2,
    unsigned short* __restrict__ Xsw, unsigned short* __restrict__ Ssw,
    unsigned short* __restrict__ Vfrag, float* __restrict__ out)
{
    const int b = blockIdx.x;
    if (b < NB_X) {
        const int id = b * 256 + threadIdx.x;
        const int row = id / 104;
        const int rem = id - row * 104;
        const int kb = rem >> 2;                 // 0..25
        const int s  = rem & 3;
        const int xi = (row ^ (row >> 2)) & 3;
        const int kk = kb * 32 + ((s ^ xi) << 3);
        bf16x8 v;
        if (kk < K_) {
            const float* xp = x + (size_t)row * K_ + kk;
            f32x4 a = *(const f32x4*)xp;
            f32x4 c = *(const f32x4*)(xp + 4);
            v[0] = (short)f2bf(a.x); v[1] = (short)f2bf(a.y);
            v[2] = (short)f2bf(a.z); v[3] = (short)f2bf(a.w);
            v[4] = (short)f2bf(c.x); v[5] = (short)f2bf(c.y);
            v[6] = (short)f2bf(c.z); v[7] = (short)f2bf(c.w);
        } else {
            v = (bf16x8)0;
        }
        *(bf16x8*)(Xsw + (size_t)row * KP + kb * 32 + s * 8) = v;
    } else if (b < NB_X + NB_S) {
        const int id = (b - NB_X) * 256 + threadIdx.x;
        const int row = id / 104;
        const int rem = id - row * 104;
        const int kb = rem >> 2;
        const int s  = rem & 3;
        const int xi = (row ^ (row >> 2)) & 3;
        const int kk = kb * 32 + ((s ^ xi) << 3);
        bf16x8 v;
        if (kk < K_) {
            const int* tp = t1 + (size_t)row * K_ + kk;
            #pragma unroll
            for (int e = 0; e < 8; ++e)
                v[e] = (short)(tp[e] ? 0x3F80 : 0xBF80);
        } else {
            v = (bf16x8)0;
        }
        *(bf16x8*)(Ssw + (size_t)row * KP + kb * 32 + s * 8) = v;
    } else if (b < NB_X + NB_S + NB_F) {
        const int id = (b - NB_X - NB_S) * 256 + threadIdx.x;   // < 16384
        const int o = id >> 10;           // 0..15 (10..15 are zero pad)
        const int r = id & 1023;
        float v = 0.f;
        if (o < OD) {
            #pragma unroll
            for (int c = 0; c < 4; ++c) {
                const int idx = o * HID + c * RP + r;
                const int ch  = idx / TS2;
                const float w2v = a2[ch] * (float)(2 * t2[idx - ch * TS2] - 1);
                v = fmaf(a1[c], w2v, v);
            }
        }
        Vfrag[(r >> 5) * 512 + (o + 16 * ((r >> 3) & 3)) * 8 + (r & 7)] = f2bf(v);
    } else {
        const int id = (b - NB_X - NB_S - NB_F) * 256 + threadIdx.x;
        ((f32x4*)out)[id] = (f32x4){0.f, 0.f, 0.f, 0.f};
    }
}

// ================= GEMM1 + fused layer 2 ==================================
// 128x128 tile, BK=32, 4-buffer LDS ring (64 KB), 3-deep prefetch with
// counted vmcnt (never 0 in loop), 1 raw barrier/step, 4 waves 2x2,
// 512 blocks XCD-chunked = 2/CU. Epilogue: relu->bf16->LDS, mini-GEMM
// vs Vfrag, atomicAdd.
__global__ __launch_bounds__(256, 2) void gemm1(const unsigned short* __restrict__ Xsw,
                                                const unsigned short* __restrict__ Ssw,
                                                const unsigned short* __restrict__ Vfrag,
                                                float* __restrict__ out) {
    __shared__ unsigned short SH[4 * 8192];      // 4 ring buffers x (A 8KB + B 8KB)

    const int tid  = threadIdx.x;
    const int lane = tid & 63;
    const int wid  = tid >> 6;

    // bijective XCD-chunked swizzle: XCD k owns bm-tiles [8k, 8k+8) x all bn
    const int swz = (blockIdx.x & 7) * 64 + (blockIdx.x >> 3);
    const int bm  = (swz >> 3) * 128;
    const int bn  = (swz & 7) * 128;

    const int wr = (wid >> 1) * 64;
    const int wc = (wid & 1) * 64;

    // fragment-read lane constants: slot = g ^ xi(r), g=lane>>4,
    // xi(r) = (r ^ (r>>2)) & 3 depends only on lane&15 (tiles 16-row aligned)
    const int sl   = (lane >> 4) ^ ((lane ^ (lane >> 2)) & 3);
    const int arow = (wr + (lane & 15)) * 32 + sl * 8;   // ushort offset, +mi*512
    const int brow = (wc + (lane & 15)) * 32 + sl * 8;   // ushort offset, +ni*512

    // staging lane constants: wave w stages 16-row chunks {2w,2w+1} of A and B
    const int schunk0 = wid * 2;
    const int srowoff = lane >> 2;               // row within 16-row chunk
    const int scol    = (lane & 3) << 3;         // ushort col offset in row

    f32x4 acc[4][4] = {};

#define STAGE(KB, BUF)                                                          \
    do {                                                                        \
        _Pragma("unroll")                                                       \
        for (int c = 0; c < 2; ++c) {                                           \
            const int chunk = schunk0 + c;                                      \
            const unsigned short* ga =                                          \
                Xsw + (size_t)(bm + chunk * 16 + srowoff) * KP + (KB) * 32 + scol; \
            const unsigned short* gb =                                          \
                Ssw + (size_t)(bn + chunk * 16 + srowoff) * KP + (KB) * 32 + scol; \
            __builtin_amdgcn_global_load_lds(                                   \
                (const __attribute__((address_space(1))) void*)ga,              \
                (__attribute__((address_space(3))) void*)                       \
                    (&SH[(BUF) * 8192 + chunk * 512 + lane * 8]), 16, 0, 0);    \
            __builtin_amdgcn_global_load_lds(                                   \
                (const __attribute__((address_space(1))) void*)gb,              \
                (__attribute__((address_space(3))) void*)                       \
                    (&SH[(BUF) * 8192 + 4096 + chunk * 512 + lane * 8]), 16, 0, 0); \
        }                                                                       \
    } while (0)

#define COMPUTE(BUF)                                                            \
    do {                                                                        \
        bf16x8 af[4], bfr[4];                                                   \
        _Pragma("unroll")                                                       \
        for (int mi = 0; mi < 4; ++mi)                                          \
            af[mi] = *(const bf16x8*)&SH[(BUF) * 8192 + arow + mi * 512];       \
        _Pragma("unroll")                                                       \
        for (int ni = 0; ni < 4; ++ni)                                          \
            bfr[ni] = *(const bf16x8*)&SH[(BUF) * 8192 + 4096 + brow + ni * 512]; \
        __builtin_amdgcn_s_setprio(1);                                          \
        _Pragma("unroll")                                                       \
        for (int mi = 0; mi < 4; ++mi)                                          \
            _Pragma("unroll")                                                   \
            for (int ni = 0; ni < 4; ++ni)                                      \
                acc[mi][ni] = __builtin_amdgcn_mfma_f32_16x16x32_bf16(          \
                    af[mi], bfr[ni], acc[mi][ni], 0, 0, 0);                     \
        __builtin_amdgcn_s_setprio(0);                                          \
    } while (0)

    // prologue: 3 tiles in flight (12 loads/wave)
    STAGE(0, 0);
    STAGE(1, 1);
    STAGE(2, 2);

    for (int kb = 0; kb < NKB - 3; ++kb) {       // kb = 0..22
        asm volatile("s_waitcnt vmcnt(8)" ::: "memory");   // tile kb landed
        __builtin_amdgcn_s_barrier();
        __builtin_amdgcn_sched_barrier(0);
        STAGE(kb + 3, (kb + 3) & 3);             // refill ring (3-deep again)
        COMPUTE(kb & 3);
    }
    // tail: kb = 23, 24, 25 (no more stages; drain counted)
    asm volatile("s_waitcnt vmcnt(8)" ::: "memory");
    __builtin_amdgcn_s_barrier();
    __builtin_amdgcn_sched_barrier(0);
    COMPUTE(3);
    asm volatile("s_waitcnt vmcnt(4)" ::: "memory");
    __builtin_amdgcn_s_barrier();
    __builtin_amdgcn_sched_barrier(0);
    COMPUTE(0);
    asm volatile("s_waitcnt vmcnt(0)" ::: "memory");
    __builtin_amdgcn_s_barrier();
    __builtin_amdgcn_sched_barrier(0);
    COMPUTE(1);
#undef STAGE
#undef COMPUTE

    // ---- fused epilogue ----------------------------------------------------
    // 1) relu(acc) -> bf16 -> Hlds[128][128] (overlay SH; col-slot XOR swizzle)
    unsigned short* Hlds = &SH[0];               // 128*128 ushorts = 32 KB
    __syncthreads();                             // all reads of SH complete
    #pragma unroll
    for (int mi = 0; mi < 4; ++mi) {
        #pragma unroll
        for (int ni = 0; ni < 4; ++ni) {
            const int col = wc + ni * 16 + (lane & 15);
            #pragma unroll
            for (int r = 0; r < 4; ++r) {
                const int row = wr + mi * 16 + (lane >> 4) * 4 + r;
                Hlds[row * 128 + ((((col >> 3) ^ (row & 7)) << 3) | (col & 7))]
                    = f2bf(fmaxf(acc[mi][ni][r], 0.f));
            }
        }
    }
    __syncthreads();

    // 2) P[128,16] = H_tile @ V_slice^T via 8 MFMAs; wave handles 2 m-frags
    const int kb0 = bn >> 5;                   // first 32-wide k-frag of this bn
    bf16x8 vb[4];
    #pragma unroll
    for (int kk = 0; kk < 4; ++kk)
        vb[kk] = *(const bf16x8*)&Vfrag[(kb0 + kk) * 512 + lane * 8];

    #pragma unroll
    for (int mf = 0; mf < 2; ++mf) {
        const int mloc = (wid * 2 + mf) * 16;  // m-frag base row (0..112)
        const int mrow = mloc + (lane & 15);
        f32x4 pac = {};
        #pragma unroll
        for (int kk = 0; kk < 4; ++kk) {
            const int slot = kk * 4 + (lane >> 4);
            bf16x8 ha = *(const bf16x8*)&Hlds[mrow * 128 + ((slot ^ (mrow & 7)) << 3)];
            pac = __builtin_amdgcn_mfma_f32_16x16x32_bf16(ha, vb[kk], pac, 0, 0, 0);
        }
        const int o = lane & 15;
        if (o < OD) {
            #pragma unroll
            for (int r = 0; r < 4; ++r) {
                const int rowg = bm + mloc + (lane >> 4) * 4 + r;
                atomicAdd(&out[(size_t)rowg * OD + o], pac[r]);
            }
        }
    }
}

// ================= fallback (round-1 f32 SIMT fused kernel) ================
#define BM 128
#define BN 128
#define BK 16
__global__ __launch_bounds__(256, 2) void fused_tilednn(
    const float* __restrict__ x, const int* __restrict__ tile1,
    const float* __restrict__ alphas1, const int* __restrict__ tile2,
    const float* __restrict__ alphas2, float* __restrict__ out)
{
    __shared__ float XsF[BK][BM];
    __shared__ float SsF[BK][BN];
    __shared__ float Vl[OD][BN];
    const int t = threadIdx.x, tx = t & 15, ty = t >> 4;
    const int bm = blockIdx.x * BM, bn = blockIdx.y * BN;
    for (int e = t; e < OD * BN; e += 256) {
        const int o = e / BN, rl = e - o * BN, rr = bn + rl;
        float v = 0.f;
        #pragma unroll
        for (int c = 0; c < 4; ++c) {
            const int idx = o * HID + c * RP + rr;
            const int ch = idx / TS2;
            v = fmaf(alphas1[c], alphas2[ch] * (float)(2 * tile2[idx - ch * TS2] - 1), v);
        }
        Vl[o][rl] = v;
    }
    float acc[8][8];
    #pragma unroll
    for (int i = 0; i < 8; ++i)
        #pragma unroll
        for (int j = 0; j < 8; ++j) acc[i][j] = 0.f;
    const int lr = t >> 1, lk = (t & 1) << 3;
    const float* xrow = x + (size_t)(bm + lr) * K_;
    const int* srow = tile1 + (size_t)(bn + lr) * K_;
    for (int k0 = 0; k0 < K_; k0 += BK) {
        __syncthreads();
        const float4 xa = *(const float4*)(xrow + k0 + lk);
        const float4 xb = *(const float4*)(xrow + k0 + lk + 4);
        const int4 sa = *(const int4*)(srow + k0 + lk);
        const int4 sb = *(const int4*)(srow + k0 + lk + 4);
        XsF[lk+0][lr]=xa.x; XsF[lk+1][lr]=xa.y; XsF[lk+2][lr]=xa.z; XsF[lk+3][lr]=xa.w;
        XsF[lk+4][lr]=xb.x; XsF[lk+5][lr]=xb.y; XsF[lk+6][lr]=xb.z; XsF[lk+7][lr]=xb.w;
        SsF[lk+0][lr]=(float)(2*sa.x-1); SsF[lk+1][lr]=(float)(2*sa.y-1);
        SsF[lk+2][lr]=(float)(2*sa.z-1); SsF[lk+3][lr]=(float)(2*sa.w-1);
        SsF[lk+4][lr]=(float)(2*sb.x-1); SsF[lk+5][lr]=(float)(2*sb.y-1);
        SsF[lk+6][lr]=(float)(2*sb.z-1); SsF[lk+7][lr]=(float)(2*sb.w-1);
        __syncthreads();
        #pragma unroll
        for (int k = 0; k < BK; ++k) {
            float av[8], bv[8];
            #pragma unroll
            for (int i = 0; i < 8; ++i) av[i] = XsF[k][ty*8+i];
            #pragma unroll
            for (int j = 0; j < 8; ++j) bv[j] = SsF[k][tx*8+j];
            #pragma unroll
            for (int i = 0; i < 8; ++i)
                #pragma unroll
                for (int j = 0; j < 8; ++j) acc[i][j] = fmaf(av[i], bv[j], acc[i][j]);
        }
    }
    #pragma unroll
    for (int i = 0; i < 8; ++i)
        #pragma unroll
        for (int j = 0; j < 8; ++j) acc[i][j] = fmaxf(acc[i][j], 0.f);
    #pragma unroll
    for (int o = 0; o < OD; ++o) {
        float vv[8];
        #pragma unroll
        for (int j = 0; j < 8; ++j) vv[j] = Vl[o][tx*8+j];
        float p[8];
        #pragma unroll
        for (int i = 0; i < 8; ++i) {
            float s = 0.f;
            #pragma unroll
            for (int j = 0; j < 8; ++j) s = fmaf(acc[i][j], vv[j], s);
            p[i] = s;
        }
        #pragma unroll
        for (int m = 8; m >= 1; m >>= 1)
            #pragma unroll
            for (int i = 0; i < 8; ++i) p[i] += __shfl_xor(p[i], m, 16);
        if (tx == 0) {
            #pragma unroll
            for (int i = 0; i < 8; ++i)
                atomicAdd(&out[(size_t)(bm + ty*8 + i) * OD + o], p[i]);
        }
    }
}

// ================= launch ==================================================
extern "C" void kernel_launch(void* const* d_in, const int* in_sizes, int n_in,
                              void* d_out, int out_size, void* d_ws, size_t ws_size,
                              hipStream_t stream) {
    const float* x       = (const float*)d_in[0];
    const int*   tile1   = (const int*)  d_in[1];
    const float* alphas1 = (const float*)d_in[2];
    const int*   tile2   = (const int*)  d_in[3];
    const float* alphas2 = (const float*)d_in[4];
    float*       out     = (float*)d_out;

    const size_t OFF_X = 0;                                   // 8192*832*2
    const size_t OFF_S = OFF_X + (size_t)B_ * KP * 2;         // + 1024*832*2
    const size_t OFF_F = OFF_S + (size_t)RP * KP * 2;         // + 16*1024*2
    const size_t NEED  = OFF_F + (size_t)16 * RP * 2;         // ~15.4 MB

    if (ws_size < NEED) {
        hipMemsetAsync(out, 0, (size_t)out_size * sizeof(float), stream);
        dim3 grid(B_ / BM, RP / BN);
        fused_tilednn<<<grid, 256, 0, stream>>>(x, tile1, alphas1, tile2, alphas2, out);
        return;
    }

    unsigned short* Xsw   = (unsigned short*)((char*)d_ws + OFF_X);
    unsigned short* Ssw   = (unsigned short*)((char*)d_ws + OFF_S);
    unsigned short* Vfrag = (unsigned short*)((char*)d_ws + OFF_F);

    prep<<<NB_X + NB_S + NB_F + NB_Z, 256, 0, stream>>>(
        x, tile1, tile2, alphas1, alphas2, Xsw, Ssw, Vfrag, out);
    gemm1<<<512, 256, 0, stream>>>(Xsw, Ssw, Vfrag, out);
}